// Round 7
// baseline (488.858 us; speedup 1.0000x reference)
//
#include <hip/hip_runtime.h>
#include <hip/hip_fp8.h>

#define DIMD 128
#define EPSV 1e-5f

typedef _Float16 f16;
typedef f16 f16x2 __attribute__((ext_vector_type(2)));
typedef f16 f16x4 __attribute__((ext_vector_type(4)));

// fp8(e4m3,OCP) x2 -> f16 x2 fast decode (exact for normals; subnormals
// decode slightly high: abs err <= 2^-7, i.e. <5e-4 after the /16 unscale)
__device__ __forceinline__ f16x2 dec8(unsigned r) {
    unsigned m = ((r & 0x7Fu) << 7) | ((r & 0x7F00u) << 15);
    unsigned h = m + 0x20002000u;
    h |= ((r & 0x80u) << 8) | ((r & 0x8000u) << 16);
    return __builtin_bit_cast(f16x2, h);
}

// ---------------- edge-index dtype probe (int64 stored vs int32) ----------
__global__ void k_detect(const int* __restrict__ ei, int nchk, int* __restrict__ mode) {
    __shared__ int any;
    if (threadIdx.x == 0) any = 0;
    __syncthreads();
    for (int i = threadIdx.x; i < nchk; i += 256)
        if (ei[2 * i + 1] != 0) any = 1;   // benign race
    __syncthreads();
    if (threadIdx.x == 0) *mode = any ? 0 : 1;  // 1 => data is int64 pairs
}

__device__ __forceinline__ int load_src(const int* ei, int e, int E, int m) {
    return m ? ei[2 * e] : ei[e];
}
__device__ __forceinline__ int load_dst(const int* ei, int e, int E, int m) {
    return m ? ei[2 * (E + e)] : ei[E + e];
}

// ---------------- latent -> fp16 copy -------------------------------------
__global__ void k_prep(const float2* __restrict__ lat, f16x2* __restrict__ lat16,
                       int total2) {
    int i = blockIdx.x * 256 + threadIdx.x;
    if (i < total2) {
        float2 v = lat[i];
        f16x2 o = {(f16)v.x, (f16)v.y};
        lat16[i] = o;
    }
}

// ---------------- rank + histogram (single atomic pass) --------------------
__global__ void k_rank(const int* __restrict__ ei, int* __restrict__ rank,
                       int* __restrict__ cnt, const int* __restrict__ modep, int E) {
    int e = blockIdx.x * 256 + threadIdx.x;
    if (e < E) {
        int m = *modep;
        int d = load_dst(ei, e, E, m);
        rank[e] = atomicAdd(&cnt[d], 1);
    }
}

// ---------------- 3-kernel exclusive scan of cnt -> offs -------------------
__global__ void k_scanA(const int* __restrict__ cnt, int* __restrict__ offs,
                        int* __restrict__ bsum, int N) {
    __shared__ int sh[256];
    int tid = threadIdx.x;
    int i = blockIdx.x * 256 + tid;
    int v = (i < N) ? cnt[i] : 0;
    sh[tid] = v;
    __syncthreads();
    for (int off = 1; off < 256; off <<= 1) {
        int t = (tid >= off) ? sh[tid - off] : 0;
        __syncthreads();
        sh[tid] += t;
        __syncthreads();
    }
    if (i < N) offs[i] = sh[tid] - v;  // exclusive
    if (tid == 255) bsum[blockIdx.x] = sh[255];
}

__global__ void k_scanB(int* __restrict__ bsum, int* __restrict__ bbase, int NB) {
    __shared__ int sh[256];
    int tid = threadIdx.x;
    int v = (tid < NB) ? bsum[tid] : 0;
    sh[tid] = v;
    __syncthreads();
    for (int off = 1; off < 256; off <<= 1) {
        int t = (tid >= off) ? sh[tid - off] : 0;
        __syncthreads();
        sh[tid] += t;
        __syncthreads();
    }
    if (tid < NB) bbase[tid] = sh[tid] - v;
}

__global__ void k_scanC(const int* __restrict__ cnt, int* __restrict__ offs,
                        const int* __restrict__ bbase, int N) {
    int i = blockIdx.x * 256 + threadIdx.x;
    if (i < N) {
        int v = offs[i] + bbase[blockIdx.x];
        offs[i] = v;
        if (i == N - 1) offs[N] = v + cnt[i];
    }
}

// ------- CSR fill (atomic-free): csr = {src, packed fp16 {w/16,w/16}} -----
__global__ void k_fill(const int* __restrict__ ei, const float* __restrict__ ew,
                       const int* __restrict__ offs, const int* __restrict__ rank,
                       int2* __restrict__ csr, const int* __restrict__ modep, int E) {
    int e = blockIdx.x * 256 + threadIdx.x;
    if (e < E) {
        int m = *modep;
        int s = load_src(ei, e, E, m);
        int d = load_dst(ei, e, E, m);
        int pos = offs[d] + rank[e];
        f16 wh = (f16)(ew[e] * 0.0625f);
        f16x2 wpk = {wh, wh};
        csr[pos] = make_int2(s, __builtin_bit_cast(int, wpk));
    }
}

// ---------------- degree from CSR (coalesced) -> dinv ----------------------
__global__ __launch_bounds__(256) void k_deg(const int2* __restrict__ csr,
                                             const int* __restrict__ offs,
                                             float* __restrict__ dinv, int N, int nwaves) {
    int lane = threadIdx.x & 63;
    int wid = blockIdx.x * 4 + (threadIdx.x >> 6);
    for (int n = wid; n < N; n += nwaves) {
        int kb = offs[n], ke = offs[n + 1];
        float s = 0.f;
        for (int e = kb + lane; e < ke; e += 64) {
            f16x2 wp = __builtin_bit_cast(f16x2, csr[e].y);
            s += (float)wp.x;
        }
        for (int off = 32; off; off >>= 1) s += __shfl_down(s, off);
        if (lane == 0) dinv[n] = rsqrtf(16.0f * s + 1.0f);
    }
}

// --- GEMM: y8[N,128] = fp8( 16 * dinv[row] * (X16[N,128] @ W + cb) ) ------
__global__ __launch_bounds__(256) void k_gemm(const f16x2* __restrict__ X16,
                                              const float* __restrict__ W,
                                              const float* __restrict__ cb,
                                              const float* __restrict__ dinv,
                                              unsigned* __restrict__ Y8, int N) {
    __shared__ float Wl[64 * 128];
    __shared__ float xl[8 * 64];
    int tid = threadIdx.x;
    int nl = tid >> 5, jg = tid & 31;
    int base = blockIdx.x * 8;
    float4 acc = {0.f, 0.f, 0.f, 0.f};
    for (int chunk = 0; chunk < 2; ++chunk) {
        int kc = chunk * 64;
        const float4* Wg = (const float4*)(W + (size_t)kc * 128);
#pragma unroll
        for (int r = 0; r < 8; r++) ((float4*)Wl)[r * 256 + tid] = Wg[r * 256 + tid];
        {
            int rr = tid >> 5;
            int kk = (tid & 31) * 2;
            int row = base + rr;
            float2 v = {0.f, 0.f};
            if (row < N) {
                f16x2 hv = X16[(size_t)row * 64 + (kc >> 1) + (tid & 31)];
                v.x = (float)hv.x;
                v.y = (float)hv.y;
            }
            xl[rr * 64 + kk] = v.x;
            xl[rr * 64 + kk + 1] = v.y;
        }
        __syncthreads();
#pragma unroll 8
        for (int k = 0; k < 64; k++) {
            float xv = xl[nl * 64 + k];
            float4 w4 = ((const float4*)Wl)[k * 32 + jg];
            acc.x += xv * w4.x;
            acc.y += xv * w4.y;
            acc.z += xv * w4.z;
            acc.w += xv * w4.w;
        }
        __syncthreads();
    }
    if (cb) {
        float4 c4 = ((const float4*)cb)[jg];
        acc.x += c4.x; acc.y += c4.y; acc.z += c4.z; acc.w += c4.w;
    }
    int n = base + nl;
    if (n < N) {
        float sc = dinv[n] * 16.0f;
        __hip_fp8x2_storage_t lo = __hip_cvt_float2_to_fp8x2(
            make_float2(acc.x * sc, acc.y * sc), __HIP_SATFINITE, __HIP_E4M3);
        __hip_fp8x2_storage_t hi = __hip_cvt_float2_to_fp8x2(
            make_float2(acc.z * sc, acc.w * sc), __HIP_SATFINITE, __HIP_E4M3);
        Y8[(size_t)n * 32 + jg] = (unsigned)lo | ((unsigned)hi << 16);
    }
}

// ------- aggregation: t = dinv*(sum w'*y8[src] + y8[n]/16) + b (...) ------
// readlane-broadcast, 8-deep unroll, fp8 gather + v_pk_fma_f16 accumulate
__global__ __launch_bounds__(256) void k_aggr(
    const unsigned short* __restrict__ y8, const f16x2* __restrict__ lat16,
    const int2* __restrict__ csr, const int* __restrict__ offs,
    const float* __restrict__ dinv, const float* __restrict__ bias,
    f16x2* __restrict__ T16, float* __restrict__ gsum, float* __restrict__ gsq,
    int N, int relu, int nwaves) {
    __shared__ float ssum[128], ssq[128];
    int tid = threadIdx.x;
    if (tid < 128) { ssum[tid] = 0.f; ssq[tid] = 0.f; }
    __syncthreads();
    int lane = tid & 63;
    int wid = blockIdx.x * 4 + (tid >> 6);
    float2 b2 = ((const float2*)bias)[lane];
    float2 ts = {0.f, 0.f}, tq = {0.f, 0.f};
    for (int n = wid; n < N; n += nwaves) {
        int kb = offs[n], ke = offs[n + 1];
        f16x2 acc_h = {(f16)0.f, (f16)0.f};
        for (int b0 = kb; b0 < ke; b0 += 64) {
            int e = b0 + lane;
            int2 v = make_int2(0, 0);
            if (e < ke) v = csr[e];
            int cnt8 = (min(64, ke - b0) + 7) & ~7;  // wave-uniform
            for (int t0 = 0; t0 < cnt8; t0 += 8) {
#pragma unroll
                for (int u = 0; u < 8; u++) {
                    int t = t0 + u;
                    int ss = __builtin_amdgcn_readlane(v.x, t);
                    int wb = __builtin_amdgcn_readlane(v.y, t);
                    f16x2 wpk = __builtin_bit_cast(f16x2, wb);
                    unsigned r = y8[(size_t)ss * 64 + lane];
                    acc_h = wpk * dec8(r) + acc_h;   // v_pk_fma_f16
                }
            }
        }
        f16x2 sv = dec8(y8[(size_t)n * 64 + lane]);
        float dv = dinv[n];
        float2 acc;
        acc.x = ((float)acc_h.x + 0.0625f * (float)sv.x) * dv + b2.x;
        acc.y = ((float)acc_h.y + 0.0625f * (float)sv.y) * dv + b2.y;
        if (relu) { acc.x = fmaxf(acc.x, 0.f); acc.y = fmaxf(acc.y, 0.f); }
        f16x2 lv = lat16[(size_t)n * 64 + lane];
        acc.x += (float)lv.x;
        acc.y += (float)lv.y;
        f16x2 to = {(f16)acc.x, (f16)acc.y};
        T16[(size_t)n * 64 + lane] = to;
        ts.x += acc.x; ts.y += acc.y;
        tq.x += acc.x * acc.x; tq.y += acc.y * acc.y;
    }
    atomicAdd(&ssum[lane * 2], ts.x);
    atomicAdd(&ssum[lane * 2 + 1], ts.y);
    atomicAdd(&ssq[lane * 2], tq.x);
    atomicAdd(&ssq[lane * 2 + 1], tq.y);
    __syncthreads();
    if (tid < 128) {
        int copy = blockIdx.x & 31;
        atomicAdd(&gsum[copy * 128 + tid], ssum[tid]);
        atomicAdd(&gsq[copy * 128 + tid], ssq[tid]);
    }
}

// ------- fused BN stats + (optional) weight/bias folding ------------------
__global__ void k_post(const float* __restrict__ gsum, const float* __restrict__ gsq,
                       const float* __restrict__ gamma, const float* __restrict__ beta,
                       const float* __restrict__ W, float* __restrict__ A,
                       float* __restrict__ C, float* __restrict__ Wf,
                       float* __restrict__ cW, int N) {
    __shared__ float As[128], Cs[128];
    int tid = threadIdx.x;  // 256
    if (tid < 128) {
        float s = 0.f, q = 0.f;
        for (int c = 0; c < 32; c++) { s += gsum[c * 128 + tid]; q += gsq[c * 128 + tid]; }
        float mean = s / (float)N;
        float var = q / (float)N - mean * mean;
        float a = gamma[tid] * rsqrtf(var + EPSV);
        float cc = beta[tid] - a * mean;
        As[tid] = a; Cs[tid] = cc;
        A[tid] = a; C[tid] = cc;
    }
    __syncthreads();
    if (W) {
        for (int i4 = tid; i4 < 4096; i4 += 256) {
            int k = i4 >> 5;
            float a = As[k];
            float4 w = ((const float4*)W)[i4];
            float4 o;
            o.x = a * w.x; o.y = a * w.y; o.z = a * w.z; o.w = a * w.w;
            ((float4*)Wf)[i4] = o;
        }
        if (tid < 128) {
            float acc = 0.f;
            for (int k = 0; k < 128; k++) acc += Cs[k] * W[k * 128 + tid];
            cW[tid] = acc;
        }
    }
}

// ---------------- final normalize of layer-2 output ------------------------
__global__ void k_bnorm(const f16x2* __restrict__ T16, const float* __restrict__ A,
                        const float* __restrict__ C, float2* __restrict__ out, int total2) {
    int i = blockIdx.x * 256 + threadIdx.x;
    if (i < total2) {
        int c = i & 63;
        f16x2 t = T16[i];
        float2 a = ((const float2*)A)[c];
        float2 cc = ((const float2*)C)[c];
        float2 r;
        r.x = a.x * (float)t.x + cc.x;
        r.y = a.y * (float)t.y + cc.y;
        out[i] = r;
    }
}

extern "C" void kernel_launch(void* const* d_in, const int* in_sizes, int n_in,
                              void* d_out, int out_size, void* d_ws, size_t ws_size,
                              hipStream_t stream) {
    const float* latent = (const float*)d_in[0];
    const int* ei = (const int*)d_in[1];
    const float* ew = (const float*)d_in[2];
    const float* Ws = (const float*)d_in[3];
    const float* bs = (const float*)d_in[4];
    const float* gammas = (const float*)d_in[5];
    const float* betas = (const float*)d_in[6];
    float* out = (float*)d_out;

    const int N = in_sizes[0] / DIMD;
    const int E = in_sizes[1] / 2;
    const int NB = (N + 255) / 256;
    const int Npad = (N + 255) & ~255;

    char* p = (char*)d_ws;
    auto alloc = [&](size_t b) -> char* {
        char* r = p;
        p += (b + 255) & ~(size_t)255;
        return r;
    };
    // ---- zero-initialized region (must stay first & contiguous) ----
    int* cnt = (int*)alloc((size_t)Npad * 4);
    float* gstats = (float*)alloc((size_t)3 * 2 * 32 * 128 * 4);  // [layer][sum/sq][copy][j]
    size_t zbytes = (size_t)(p - (char*)d_ws);
    // ---- rest ----
    int* mode = (int*)alloc(256);
    float* dinv = (float*)alloc((size_t)N * 4);
    int* offs = (int*)alloc((size_t)(N + 1) * 4);
    int* bsum = (int*)alloc(256 * 4);
    int* bbase = (int*)alloc(256 * 4);
    float* A = (float*)alloc(128 * 4);
    float* C = (float*)alloc(128 * 4);
    float* cW = (float*)alloc(128 * 4);
    float* Wf = (float*)alloc((size_t)128 * 128 * 4);
    int* rank = (int*)alloc((size_t)E * 4);
    int2* csr = (int2*)alloc((size_t)E * 8);
    unsigned* bufY8 = (unsigned*)alloc((size_t)N * DIMD);      // y (fp8 e4m3, x16)
    f16x2* lat16 = (f16x2*)alloc((size_t)N * DIMD * 2);        // latent (fp16)
    f16x2* bufB16 = (f16x2*)alloc((size_t)N * DIMD * 2);       // t (fp16)

    hipMemsetAsync(d_ws, 0, zbytes, stream);

    int nchk = E < 4096 ? E : 4096;
    int total2 = N * (DIMD / 2);
    k_detect<<<1, 256, 0, stream>>>(ei, nchk, mode);
    k_prep<<<(total2 + 255) / 256, 256, 0, stream>>>((const float2*)latent, lat16, total2);
    k_rank<<<(E + 255) / 256, 256, 0, stream>>>(ei, rank, cnt, mode, E);
    k_scanA<<<NB, 256, 0, stream>>>(cnt, offs, bsum, N);
    k_scanB<<<1, 256, 0, stream>>>(bsum, bbase, NB);
    k_scanC<<<NB, 256, 0, stream>>>(cnt, offs, bbase, N);
    k_fill<<<(E + 255) / 256, 256, 0, stream>>>(ei, ew, offs, rank, csr, mode, E);
    k_deg<<<512, 256, 0, stream>>>(csr, offs, dinv, N, 2048);

    const f16x2* gin = lat16;
    for (int i = 0; i < 3; i++) {
        const float* Wp = (i == 0) ? Ws : Wf;
        const float* cbp = (i == 0) ? nullptr : cW;
        k_gemm<<<(N + 7) / 8, 256, 0, stream>>>(gin, Wp, cbp, dinv, bufY8, N);
        float* gsum_i = gstats + (size_t)i * 2 * 32 * 128;
        float* gsq_i = gsum_i + 32 * 128;
        k_aggr<<<2048, 256, 0, stream>>>((const unsigned short*)bufY8, lat16, csr, offs,
                                         dinv, bs + i * DIMD, bufB16, gsum_i, gsq_i, N,
                                         (i != 1) ? 1 : 0, 8192);
        const float* Wnext = (i < 2) ? (Ws + (size_t)(i + 1) * DIMD * DIMD) : nullptr;
        k_post<<<1, 256, 0, stream>>>(gsum_i, gsq_i, gammas + i * DIMD, betas + i * DIMD,
                                      Wnext, A, C, Wf, cW, N);
        if (i < 2) gin = bufB16;  // next GEMM consumes un-normalized t (fp16)
    }
    k_bnorm<<<(total2 + 255) / 256, 256, 0, stream>>>(bufB16, A, C, (float2*)out, total2);
}

// Round 8
// 421.436 us; speedup vs baseline: 1.1600x; 1.1600x over previous
//
#include <hip/hip_runtime.h>
#include <hip/hip_fp8.h>

#define DIMD 128
#define EPSV 1e-5f

typedef _Float16 f16;
typedef f16 f16x2 __attribute__((ext_vector_type(2)));
typedef float f32x2 __attribute__((ext_vector_type(2)));

// ---------------- edge-index dtype probe (int64 stored vs int32) ----------
__global__ void k_detect(const int* __restrict__ ei, int nchk, int* __restrict__ mode) {
    __shared__ int any;
    if (threadIdx.x == 0) any = 0;
    __syncthreads();
    for (int i = threadIdx.x; i < nchk; i += 256)
        if (ei[2 * i + 1] != 0) any = 1;   // benign race
    __syncthreads();
    if (threadIdx.x == 0) *mode = any ? 0 : 1;  // 1 => data is int64 pairs
}

__device__ __forceinline__ int load_src(const int* ei, int e, int E, int m) {
    return m ? ei[2 * e] : ei[e];
}
__device__ __forceinline__ int load_dst(const int* ei, int e, int E, int m) {
    return m ? ei[2 * (E + e)] : ei[E + e];
}

// ---------------- latent -> fp16 copy -------------------------------------
__global__ void k_prep(const float2* __restrict__ lat, f16x2* __restrict__ lat16,
                       int total2) {
    int i = blockIdx.x * 256 + threadIdx.x;
    if (i < total2) {
        float2 v = lat[i];
        f16x2 o = {(f16)v.x, (f16)v.y};
        lat16[i] = o;
    }
}

// ---------------- rank + histogram (single atomic pass) --------------------
__global__ void k_rank(const int* __restrict__ ei, int* __restrict__ rank,
                       int* __restrict__ cnt, const int* __restrict__ modep, int E) {
    int e = blockIdx.x * 256 + threadIdx.x;
    if (e < E) {
        int m = *modep;
        int d = load_dst(ei, e, E, m);
        rank[e] = atomicAdd(&cnt[d], 1);
    }
}

// ---------------- 3-kernel exclusive scan of cnt -> offs -------------------
__global__ void k_scanA(const int* __restrict__ cnt, int* __restrict__ offs,
                        int* __restrict__ bsum, int N) {
    __shared__ int sh[256];
    int tid = threadIdx.x;
    int i = blockIdx.x * 256 + tid;
    int v = (i < N) ? cnt[i] : 0;
    sh[tid] = v;
    __syncthreads();
    for (int off = 1; off < 256; off <<= 1) {
        int t = (tid >= off) ? sh[tid - off] : 0;
        __syncthreads();
        sh[tid] += t;
        __syncthreads();
    }
    if (i < N) offs[i] = sh[tid] - v;  // exclusive
    if (tid == 255) bsum[blockIdx.x] = sh[255];
}

__global__ void k_scanB(int* __restrict__ bsum, int* __restrict__ bbase, int NB) {
    __shared__ int sh[256];
    int tid = threadIdx.x;
    int v = (tid < NB) ? bsum[tid] : 0;
    sh[tid] = v;
    __syncthreads();
    for (int off = 1; off < 256; off <<= 1) {
        int t = (tid >= off) ? sh[tid - off] : 0;
        __syncthreads();
        sh[tid] += t;
        __syncthreads();
    }
    if (tid < NB) bbase[tid] = sh[tid] - v;
}

__global__ void k_scanC(const int* __restrict__ cnt, int* __restrict__ offs,
                        const int* __restrict__ bbase, int N) {
    int i = blockIdx.x * 256 + threadIdx.x;
    if (i < N) {
        int v = offs[i] + bbase[blockIdx.x];
        offs[i] = v;
        if (i == N - 1) offs[N] = v + cnt[i];
    }
}

// ------- CSR fill (atomic-free): csr = {src, f32 w/16} --------------------
__global__ void k_fill(const int* __restrict__ ei, const float* __restrict__ ew,
                       const int* __restrict__ offs, const int* __restrict__ rank,
                       int2* __restrict__ csr, const int* __restrict__ modep, int E) {
    int e = blockIdx.x * 256 + threadIdx.x;
    if (e < E) {
        int m = *modep;
        int s = load_src(ei, e, E, m);
        int d = load_dst(ei, e, E, m);
        int pos = offs[d] + rank[e];
        csr[pos] = make_int2(s, __float_as_int(ew[e] * 0.0625f));
    }
}

// ---------------- degree from CSR (coalesced) -> dinv ----------------------
__global__ __launch_bounds__(256) void k_deg(const int2* __restrict__ csr,
                                             const int* __restrict__ offs,
                                             float* __restrict__ dinv, int N, int nwaves) {
    int lane = threadIdx.x & 63;
    int wid = blockIdx.x * 4 + (threadIdx.x >> 6);
    for (int n = wid; n < N; n += nwaves) {
        int kb = offs[n], ke = offs[n + 1];
        float s = 0.f;
        for (int e = kb + lane; e < ke; e += 64) s += __int_as_float(csr[e].y);
        for (int off = 32; off; off >>= 1) s += __shfl_down(s, off);
        if (lane == 0) dinv[n] = rsqrtf(16.0f * s + 1.0f);
    }
}

// --- GEMM: y8[N,128] = fp8( 16 * dinv[row] * (X16[N,128] @ W + cb) ) ------
__global__ __launch_bounds__(256) void k_gemm(const f16x2* __restrict__ X16,
                                              const float* __restrict__ W,
                                              const float* __restrict__ cb,
                                              const float* __restrict__ dinv,
                                              unsigned* __restrict__ Y8, int N) {
    __shared__ float Wl[64 * 128];
    __shared__ float xl[8 * 64];
    int tid = threadIdx.x;
    int nl = tid >> 5, jg = tid & 31;
    int base = blockIdx.x * 8;
    float4 acc = {0.f, 0.f, 0.f, 0.f};
    for (int chunk = 0; chunk < 2; ++chunk) {
        int kc = chunk * 64;
        const float4* Wg = (const float4*)(W + (size_t)kc * 128);
#pragma unroll
        for (int r = 0; r < 8; r++) ((float4*)Wl)[r * 256 + tid] = Wg[r * 256 + tid];
        {
            int rr = tid >> 5;
            int kk = (tid & 31) * 2;
            int row = base + rr;
            float2 v = {0.f, 0.f};
            if (row < N) {
                f16x2 hv = X16[(size_t)row * 64 + (kc >> 1) + (tid & 31)];
                v.x = (float)hv.x;
                v.y = (float)hv.y;
            }
            xl[rr * 64 + kk] = v.x;
            xl[rr * 64 + kk + 1] = v.y;
        }
        __syncthreads();
#pragma unroll 8
        for (int k = 0; k < 64; k++) {
            float xv = xl[nl * 64 + k];
            float4 w4 = ((const float4*)Wl)[k * 32 + jg];
            acc.x += xv * w4.x;
            acc.y += xv * w4.y;
            acc.z += xv * w4.z;
            acc.w += xv * w4.w;
        }
        __syncthreads();
    }
    if (cb) {
        float4 c4 = ((const float4*)cb)[jg];
        acc.x += c4.x; acc.y += c4.y; acc.z += c4.z; acc.w += c4.w;
    }
    int n = base + nl;
    if (n < N) {
        float sc = dinv[n] * 16.0f;
        __hip_fp8x2_storage_t lo = __hip_cvt_float2_to_fp8x2(
            make_float2(acc.x * sc, acc.y * sc), __HIP_SATFINITE, __HIP_E4M3);
        __hip_fp8x2_storage_t hi = __hip_cvt_float2_to_fp8x2(
            make_float2(acc.z * sc, acc.w * sc), __HIP_SATFINITE, __HIP_E4M3);
        Y8[(size_t)n * 32 + jg] = (unsigned)lo | ((unsigned)hi << 16);
    }
}

// ------- aggregation: t = dinv*(sum w'*y8[src] + y8[n]/16) + b (...) ------
// readlane-broadcast, 8-deep unroll, HW fp8->f32 cvt, f32 accumulate,
// 32-bit saddr offsets (no per-edge 64-bit address chain)
__global__ __launch_bounds__(256) void k_aggr(
    const unsigned short* __restrict__ y8, const f16x2* __restrict__ lat16,
    const int2* __restrict__ csr, const int* __restrict__ offs,
    const float* __restrict__ dinv, const float* __restrict__ bias,
    f16x2* __restrict__ T16, float* __restrict__ gsum, float* __restrict__ gsq,
    int N, int relu, int nwaves) {
    __shared__ float ssum[128], ssq[128];
    int tid = threadIdx.x;
    if (tid < 128) { ssum[tid] = 0.f; ssq[tid] = 0.f; }
    __syncthreads();
    unsigned lane = tid & 63;
    int wid = blockIdx.x * 4 + (tid >> 6);
    float2 b2 = ((const float2*)bias)[lane];
    float2 ts = {0.f, 0.f}, tq = {0.f, 0.f};
    for (int n = wid; n < N; n += nwaves) {
        int kb = offs[n], ke = offs[n + 1];
        float2 acc = {0.f, 0.f};
        for (int b0 = kb; b0 < ke; b0 += 64) {
            int e = b0 + (int)lane;
            int2 v = make_int2(0, 0);
            if (e < ke) v = csr[e];
            int cnt8 = (min(64, ke - b0) + 7) & ~7;  // wave-uniform
            for (int t0 = 0; t0 < cnt8; t0 += 8) {
#pragma unroll
                for (int u = 0; u < 8; u++) {
                    int t = t0 + u;
                    unsigned ss = (unsigned)__builtin_amdgcn_readlane(v.x, t);
                    float ww = __uint_as_float(
                        (unsigned)__builtin_amdgcn_readlane(v.y, t));
                    unsigned r = y8[(ss << 6) | lane];   // 32-bit voffset
                    f32x2 yv = __builtin_amdgcn_cvt_pk_f32_fp8(r, false);
                    acc.x += ww * yv.x;
                    acc.y += ww * yv.y;
                }
            }
        }
        f32x2 sv = __builtin_amdgcn_cvt_pk_f32_fp8(
            (unsigned)y8[((unsigned)n << 6) | lane], false);
        float dv = dinv[n];
        acc.x = (acc.x + 0.0625f * sv.x) * dv + b2.x;
        acc.y = (acc.y + 0.0625f * sv.y) * dv + b2.y;
        if (relu) { acc.x = fmaxf(acc.x, 0.f); acc.y = fmaxf(acc.y, 0.f); }
        f16x2 lv = lat16[((unsigned)n << 6) | lane];
        acc.x += (float)lv.x;
        acc.y += (float)lv.y;
        f16x2 to = {(f16)acc.x, (f16)acc.y};
        T16[((unsigned)n << 6) | lane] = to;
        ts.x += acc.x; ts.y += acc.y;
        tq.x += acc.x * acc.x; tq.y += acc.y * acc.y;
    }
    atomicAdd(&ssum[lane * 2], ts.x);
    atomicAdd(&ssum[lane * 2 + 1], ts.y);
    atomicAdd(&ssq[lane * 2], tq.x);
    atomicAdd(&ssq[lane * 2 + 1], tq.y);
    __syncthreads();
    if (tid < 128) {
        int copy = blockIdx.x & 31;
        atomicAdd(&gsum[copy * 128 + tid], ssum[tid]);
        atomicAdd(&gsq[copy * 128 + tid], ssq[tid]);
    }
}

// ------- fused BN stats + (optional) weight/bias folding ------------------
__global__ void k_post(const float* __restrict__ gsum, const float* __restrict__ gsq,
                       const float* __restrict__ gamma, const float* __restrict__ beta,
                       const float* __restrict__ W, float* __restrict__ A,
                       float* __restrict__ C, float* __restrict__ Wf,
                       float* __restrict__ cW, int N) {
    __shared__ float As[128], Cs[128];
    int tid = threadIdx.x;  // 256
    if (tid < 128) {
        float s = 0.f, q = 0.f;
        for (int c = 0; c < 32; c++) { s += gsum[c * 128 + tid]; q += gsq[c * 128 + tid]; }
        float mean = s / (float)N;
        float var = q / (float)N - mean * mean;
        float a = gamma[tid] * rsqrtf(var + EPSV);
        float cc = beta[tid] - a * mean;
        As[tid] = a; Cs[tid] = cc;
        A[tid] = a; C[tid] = cc;
    }
    __syncthreads();
    if (W) {
        for (int i4 = tid; i4 < 4096; i4 += 256) {
            int k = i4 >> 5;
            float a = As[k];
            float4 w = ((const float4*)W)[i4];
            float4 o;
            o.x = a * w.x; o.y = a * w.y; o.z = a * w.z; o.w = a * w.w;
            ((float4*)Wf)[i4] = o;
        }
        if (tid < 128) {
            float acc = 0.f;
            for (int k = 0; k < 128; k++) acc += Cs[k] * W[k * 128 + tid];
            cW[tid] = acc;
        }
    }
}

// ---------------- final normalize of layer-2 output ------------------------
__global__ void k_bnorm(const f16x2* __restrict__ T16, const float* __restrict__ A,
                        const float* __restrict__ C, float2* __restrict__ out, int total2) {
    int i = blockIdx.x * 256 + threadIdx.x;
    if (i < total2) {
        int c = i & 63;
        f16x2 t = T16[i];
        float2 a = ((const float2*)A)[c];
        float2 cc = ((const float2*)C)[c];
        float2 r;
        r.x = a.x * (float)t.x + cc.x;
        r.y = a.y * (float)t.y + cc.y;
        out[i] = r;
    }
}

extern "C" void kernel_launch(void* const* d_in, const int* in_sizes, int n_in,
                              void* d_out, int out_size, void* d_ws, size_t ws_size,
                              hipStream_t stream) {
    const float* latent = (const float*)d_in[0];
    const int* ei = (const int*)d_in[1];
    const float* ew = (const float*)d_in[2];
    const float* Ws = (const float*)d_in[3];
    const float* bs = (const float*)d_in[4];
    const float* gammas = (const float*)d_in[5];
    const float* betas = (const float*)d_in[6];
    float* out = (float*)d_out;

    const int N = in_sizes[0] / DIMD;
    const int E = in_sizes[1] / 2;
    const int NB = (N + 255) / 256;
    const int Npad = (N + 255) & ~255;

    char* p = (char*)d_ws;
    auto alloc = [&](size_t b) -> char* {
        char* r = p;
        p += (b + 255) & ~(size_t)255;
        return r;
    };
    // ---- zero-initialized region (must stay first & contiguous) ----
    int* cnt = (int*)alloc((size_t)Npad * 4);
    float* gstats = (float*)alloc((size_t)3 * 2 * 32 * 128 * 4);  // [layer][sum/sq][copy][j]
    size_t zbytes = (size_t)(p - (char*)d_ws);
    // ---- rest ----
    int* mode = (int*)alloc(256);
    float* dinv = (float*)alloc((size_t)N * 4);
    int* offs = (int*)alloc((size_t)(N + 1) * 4);
    int* bsum = (int*)alloc(256 * 4);
    int* bbase = (int*)alloc(256 * 4);
    float* A = (float*)alloc(128 * 4);
    float* C = (float*)alloc(128 * 4);
    float* cW = (float*)alloc(128 * 4);
    float* Wf = (float*)alloc((size_t)128 * 128 * 4);
    int* rank = (int*)alloc((size_t)E * 4);
    int2* csr = (int2*)alloc((size_t)E * 8);
    unsigned* bufY8 = (unsigned*)alloc((size_t)N * DIMD);      // y (fp8 e4m3, x16)
    f16x2* lat16 = (f16x2*)alloc((size_t)N * DIMD * 2);        // latent (fp16)
    f16x2* bufB16 = (f16x2*)alloc((size_t)N * DIMD * 2);       // t (fp16)

    hipMemsetAsync(d_ws, 0, zbytes, stream);

    int nchk = E < 4096 ? E : 4096;
    int total2 = N * (DIMD / 2);
    k_detect<<<1, 256, 0, stream>>>(ei, nchk, mode);
    k_prep<<<(total2 + 255) / 256, 256, 0, stream>>>((const float2*)latent, lat16, total2);
    k_rank<<<(E + 255) / 256, 256, 0, stream>>>(ei, rank, cnt, mode, E);
    k_scanA<<<NB, 256, 0, stream>>>(cnt, offs, bsum, N);
    k_scanB<<<1, 256, 0, stream>>>(bsum, bbase, NB);
    k_scanC<<<NB, 256, 0, stream>>>(cnt, offs, bbase, N);
    k_fill<<<(E + 255) / 256, 256, 0, stream>>>(ei, ew, offs, rank, csr, mode, E);
    k_deg<<<512, 256, 0, stream>>>(csr, offs, dinv, N, 2048);

    const f16x2* gin = lat16;
    for (int i = 0; i < 3; i++) {
        const float* Wp = (i == 0) ? Ws : Wf;
        const float* cbp = (i == 0) ? nullptr : cW;
        k_gemm<<<(N + 7) / 8, 256, 0, stream>>>(gin, Wp, cbp, dinv, bufY8, N);
        float* gsum_i = gstats + (size_t)i * 2 * 32 * 128;
        float* gsq_i = gsum_i + 32 * 128;
        k_aggr<<<2048, 256, 0, stream>>>((const unsigned short*)bufY8, lat16, csr, offs,
                                         dinv, bs + i * DIMD, bufB16, gsum_i, gsq_i, N,
                                         (i != 1) ? 1 : 0, 8192);
        const float* Wnext = (i < 2) ? (Ws + (size_t)(i + 1) * DIMD * DIMD) : nullptr;
        k_post<<<1, 256, 0, stream>>>(gsum_i, gsq_i, gammas + i * DIMD, betas + i * DIMD,
                                      Wnext, A, C, Wf, cW, N);
        if (i < 2) gin = bufB16;  // next GEMM consumes un-normalized t (fp16)
    }
    k_bnorm<<<(total2 + 255) / 256, 256, 0, stream>>>(bufB16, A, C, (float2*)out, total2);
}